// Round 9
// baseline (429.767 us; speedup 1.0000x reference)
//
#include <hip/hip_runtime.h>
#include <cstdint>

#define BB 4
#define NN 4096
#define CC 256

typedef __attribute__((ext_vector_type(8))) short bf16x8;
typedef __attribute__((ext_vector_type(4))) short bf16x4;
typedef __attribute__((ext_vector_type(4))) float f32x4;
typedef unsigned int u32;
typedef __attribute__((ext_vector_type(4))) u32 u32x4;
typedef __attribute__((ext_vector_type(2))) u32 u32x2;

#define MFMA_FP8(a, b, c)  __builtin_amdgcn_mfma_f32_16x16x32_fp8_fp8((a), (b), (c), 0, 0, 0)

// gfx9 s_waitcnt immediate: vmcnt[3:0]+[15:14], expcnt[6:4], lgkmcnt[11:8]
#define WAITCNT(vm, xp, lgkm) (((vm) & 0xF) | (((vm) >> 4) << 14) | ((xp) << 4) | ((lgkm) << 8))

__device__ __forceinline__ unsigned short f2bf(float f) {
  union { float f; unsigned u; } v; v.f = f;
  unsigned r = v.u + 0x7fffu + ((v.u >> 16) & 1u);
  return (unsigned short)(r >> 16);
}
// pack 4 f32 -> 4 fp8 e4m3 (OCP) in one dword, byte order a,b,c,d
__device__ __forceinline__ u32 pk4_fp8(float a, float b, float c, float d) {
  u32 v = (u32)__builtin_amdgcn_cvt_pk_fp8_f32(a, b, 0, false);
  v = (u32)__builtin_amdgcn_cvt_pk_fp8_f32(c, d, (int)v, true);
  return v;
}
__device__ __forceinline__ unsigned char fp8_1(float a) {
  return (unsigned char)(((u32)__builtin_amdgcn_cvt_pk_fp8_f32(a, a, 0, false)) & 0xff);
}

typedef __attribute__((address_space(3))) unsigned int lds_u32;
typedef __attribute__((address_space(1))) unsigned int glb_u32;

// async global->LDS, 16B per lane; LDS dest = wave-uniform base + lane*16
__device__ __forceinline__ void async_cp16(const void* g, void* l) {
  __builtin_amdgcn_global_load_lds((const glb_u32*)g,
                                   (lds_u32*)(unsigned)(unsigned long long)l,
                                   16, 0, 0);
}

// ---------------- W transpose: Wt8[z][d][c] = fp8(W_z[c][d]) ----------------
__global__ __launch_bounds__(256) void transpose_w(const float* __restrict__ Wq,
                                                   const float* __restrict__ Wk,
                                                   const float* __restrict__ Wv,
                                                   unsigned char* __restrict__ Wt8) {
  __shared__ float sT[64 * 65];
  int blk = blockIdx.x;            // 48 = 3 * 16
  int z = blk / 16, tl = blk % 16;
  int c0 = (tl >> 2) * 64, d0 = (tl & 3) * 64;
  const float* W = (z == 0) ? Wq : ((z == 1) ? Wk : Wv);
  #pragma unroll
  for (int i = 0; i < 16; ++i) {
    int e = i * 256 + threadIdx.x;
    int c = e >> 6, d = e & 63;
    sT[c * 65 + d] = W[(size_t)(c0 + c) * CC + d0 + d];
  }
  __syncthreads();
  #pragma unroll
  for (int i = 0; i < 16; ++i) {
    int e = i * 256 + threadIdx.x;
    int d = e >> 6, c = e & 63;
    Wt8[(size_t)z * 65536 + (size_t)(d0 + d) * CC + c0 + c] = fp8_1(sT[c * 65 + d]);
  }
}

// ---------------- instance-norm stats ----------------
__global__ __launch_bounds__(256) void stats_partial(const float* __restrict__ content,
                                                     const float* __restrict__ style,
                                                     float* __restrict__ sums) {
  int blk = blockIdx.x;                 // 1024 blocks: [t:2][b:4][chunk:128]
  int t = blk >> 9, b = (blk >> 7) & 3, chunk = blk & 127;
  const float* X = t ? style : content;
  int c = threadIdx.x;
  const float* base = X + ((size_t)b * NN + (size_t)chunk * 32) * CC + c;
  float s = 0.f, ss = 0.f;
  #pragma unroll 8
  for (int r = 0; r < 32; ++r) {
    float x = base[(size_t)r * CC];
    s += x; ss += x * x;
  }
  atomicAdd(&sums[((t * 2 + 0) * BB + b) * CC + c], s);
  atomicAdd(&sums[((t * 2 + 1) * BB + b) * CC + c], ss);
}

__global__ __launch_bounds__(256) void stats_finalize(const float* __restrict__ sums,
                                                      float* __restrict__ stats) {
  int i = blockIdx.x * 256 + threadIdx.x;   // 2048 = 2*B*C
  int t = i >> 10, bc = i & 1023;
  float s = sums[(t * 2 + 0) * 1024 + bc];
  float ss = sums[(t * 2 + 1) * 1024 + bc];
  float m = s * (1.0f / NN);
  float var = ss * (1.0f / NN) - m * m;
  stats[(t * 2 + 0) * 1024 + bc] = m;
  stats[(t * 2 + 1) * 1024 + bc] = rsqrtf(var + 1e-5f);
}

// ---------------- QKV: fp8 GEMM, 128-row x 256-col tiles, 256 thr, 2 blocks/CU ----------------
// Vct output layout (flash-read-optimal tiles):
//   Vct[b][ktile:64][ks:2][quad:4][ch:512][key8:8] fp8, 2 MB per batch.
//   key within 64-key tile = ks*32 + quad*8 + key8; ch<256: V, ch>=256: V^2.
__global__ __launch_bounds__(256, 2) void qkv_kernel(
    const float* __restrict__ content, const float* __restrict__ style,
    const unsigned char* __restrict__ Wt8,
    const float* __restrict__ bq, const float* __restrict__ bk, const float* __restrict__ bv,
    const float* __restrict__ stats,
    unsigned char* __restrict__ Qn, unsigned char* __restrict__ Kn,
    unsigned char* __restrict__ Vct) {
  __shared__ __align__(16) char sW[32768];   // [256 d][128 c] fp8, slot8 = c16 ^ (d&7)
  __shared__ __align__(16) char sX[32768];   // [128 r][256 c] fp8, slot16 = c16 ^ (r&15); V-epilogue alias sOT[256][128]

  int tid = threadIdx.x;
  int wid = tid >> 6, lane = tid & 63, quad = lane >> 4, l16 = lane & 15;
  int uwid = __builtin_amdgcn_readfirstlane(wid);
  int tileid = blockIdx.x;      // 0..127 over B*N/128
  int z = blockIdx.y;           // 0=Q 1=K 2=V
  int gr0 = tileid * 128;       // global row over B*N
  int b = gr0 >> 12;

  const float* X = (z == 0) ? content : style;
  int statt = (z == 0) ? 0 : 1;
  const float* mean = stats + ((statt * 2 + 0) * BB + b) * CC;
  const float* rstd = stats + ((statt * 2 + 1) * BB + b) * CC;
  bool donorm = (z < 2);

  // ---- stage sX: x-hat (or raw style for V) quantized to fp8, swizzled ----
  #pragma unroll
  for (int i = 0; i < 8; ++i) {
    int lin = i * 256 + tid;
    int row = lin >> 4, c16 = lin & 15;
    int c = c16 * 16;
    const float* xr = X + (size_t)(gr0 + row) * CC + c;
    f32x4 x0 = *(const f32x4*)(xr + 0);
    f32x4 x1 = *(const f32x4*)(xr + 4);
    f32x4 x2 = *(const f32x4*)(xr + 8);
    f32x4 x3 = *(const f32x4*)(xr + 12);
    if (donorm) {
      f32x4 m0 = *(const f32x4*)(mean + c + 0), r0 = *(const f32x4*)(rstd + c + 0);
      f32x4 m1 = *(const f32x4*)(mean + c + 4), r1 = *(const f32x4*)(rstd + c + 4);
      f32x4 m2 = *(const f32x4*)(mean + c + 8), r2 = *(const f32x4*)(rstd + c + 8);
      f32x4 m3 = *(const f32x4*)(mean + c + 12), r3 = *(const f32x4*)(rstd + c + 12);
      x0 = (x0 - m0) * r0; x1 = (x1 - m1) * r1;
      x2 = (x2 - m2) * r2; x3 = (x3 - m3) * r3;
    }
    u32x4 pk;
    pk.x = pk4_fp8(x0.x, x0.y, x0.z, x0.w);
    pk.y = pk4_fp8(x1.x, x1.y, x1.z, x1.w);
    pk.z = pk4_fp8(x2.x, x2.y, x2.z, x2.w);
    pk.w = pk4_fp8(x3.x, x3.y, x3.z, x3.w);
    *(u32x4*)(sX + row * 256 + ((c16 ^ (row & 15)) * 16)) = pk;
  }

  f32x4 zero4 = {0.f, 0.f, 0.f, 0.f};
  f32x4 acc[2][16];
  #pragma unroll
  for (int i = 0; i < 2; ++i)
    #pragma unroll
    for (int j = 0; j < 16; ++j) acc[i][j] = zero4;

  const unsigned char* wb = Wt8 + (size_t)z * 65536;

  for (int half = 0; half < 2; ++half) {
    __syncthreads();   // sX visible (half0) / sW reads of prior half done (half1)
    // stage sW half: [256 d][128 c] fp8 from Wt8[z][d][half*128+..]
    #pragma unroll
    for (int it = 0; it < 8; ++it) {
      int L = it * 256 + wid * 64 + lane;
      int d = L >> 3;
      int c16 = (L & 7) ^ (d & 7);
      async_cp16(wb + (size_t)d * 256 + half * 128 + c16 * 16,
                 sW + (size_t)(it * 256 + uwid * 64) * 16);
    }
    __syncthreads();   // drain (compiler emits vmcnt(0) before barrier)

    // A-frags: rows wid*32 + mf*16 + l16, k-chunks kc*32 + quad*8 within this half
    long a[2][4];
    #pragma unroll
    for (int mf = 0; mf < 2; ++mf) {
      int row = wid * 32 + mf * 16 + l16;
      #pragma unroll
      for (int kc = 0; kc < 4; ++kc) {
        int chunk = half * 8 + kc * 2 + (quad >> 1);
        a[mf][kc] = *(const long*)(sX + row * 256 + ((chunk ^ (row & 15)) * 16) + (quad & 1) * 8);
      }
    }
    #pragma unroll
    for (int nf = 0; nf < 16; ++nf) {
      int d = nf * 16 + l16;
      #pragma unroll
      for (int kc = 0; kc < 4; ++kc) {
        long bw = *(const long*)(sW + d * 128 + (((kc * 2 + (quad >> 1)) ^ (d & 7)) * 16) + (quad & 1) * 8);
        acc[0][nf] = MFMA_FP8(a[0][kc], bw, acc[0][nf]);
        acc[1][nf] = MFMA_FP8(a[1][kc], bw, acc[1][nf]);
      }
    }
  }

  // ---- bias (before l2norm / store) ----
  const float* bias = (z == 0) ? bq : ((z == 1) ? bk : bv);
  #pragma unroll
  for (int nf = 0; nf < 16; ++nf) {
    float bb_ = bias[nf * 16 + l16];
    #pragma unroll
    for (int mf = 0; mf < 2; ++mf) {
      acc[mf][nf].x += bb_; acc[mf][nf].y += bb_;
      acc[mf][nf].z += bb_; acc[mf][nf].w += bb_;
    }
  }

  if (z < 2) {
    // l2-normalize rows (sum over all 256 cols lives in this wave), store fp8 row-major
    unsigned char* O = (z == 0) ? Qn : Kn;
    #pragma unroll
    for (int mf = 0; mf < 2; ++mf) {
      f32x4 ss = zero4;
      #pragma unroll
      for (int nf = 0; nf < 16; ++nf) ss += acc[mf][nf] * acc[mf][nf];
      #pragma unroll
      for (int m = 1; m < 16; m <<= 1) {
        ss.x += __shfl_xor(ss.x, m, 64);
        ss.y += __shfl_xor(ss.y, m, 64);
        ss.z += __shfl_xor(ss.z, m, 64);
        ss.w += __shfl_xor(ss.w, m, 64);
      }
      f32x4 rq;
      rq.x = rsqrtf(ss.x + 1e-12f); rq.y = rsqrtf(ss.y + 1e-12f);
      rq.z = rsqrtf(ss.z + 1e-12f); rq.w = rsqrtf(ss.w + 1e-12f);
      int r0 = wid * 32 + mf * 16 + quad * 4;
      #pragma unroll
      for (int nf = 0; nf < 16; ++nf) {
        int col = nf * 16 + l16;
        u32 p01 = (u32)__builtin_amdgcn_cvt_pk_fp8_f32(acc[mf][nf].x * rq.x, acc[mf][nf].y * rq.y, 0, false);
        u32 p23 = (u32)__builtin_amdgcn_cvt_pk_fp8_f32(acc[mf][nf].z * rq.z, acc[mf][nf].w * rq.w, 0, false);
        O[(size_t)(gr0 + r0 + 0) * CC + col] = (unsigned char)(p01 & 0xff);
        O[(size_t)(gr0 + r0 + 1) * CC + col] = (unsigned char)((p01 >> 8) & 0xff);
        O[(size_t)(gr0 + r0 + 2) * CC + col] = (unsigned char)(p23 & 0xff);
        O[(size_t)(gr0 + r0 + 3) * CC + col] = (unsigned char)((p23 >> 8) & 0xff);
      }
    }
  } else {
    // V: two passes through sOT (alias sX): pass0 = V, pass1 = V^2.
    // Store to tiled Vct[b][ktile][ks][quad][ch][8]; 8B stores, ch-contiguous across threads.
    char* sOT = sX;   // [256 ch][128 row] fp8, chunk j' = j ^ (ch&7)
    int n_in_b = gr0 & (NN - 1);        // multiple of 128
    int ktbase = n_in_b >> 6;           // first of 2 ktiles covered by this 128-row window
    __syncthreads();   // all sX A-reads done
    #pragma unroll
    for (int pass = 0; pass < 2; ++pass) {
      #pragma unroll
      for (int mf = 0; mf < 2; ++mf) {
        int j = wid * 2 + mf;
        #pragma unroll
        for (int nf = 0; nf < 16; ++nf) {
          int col = nf * 16 + l16;
          f32x4 v = acc[mf][nf];
          f32x4 w = pass ? (v * v) : v;
          u32 pk = pk4_fp8(w.x, w.y, w.z, w.w);
          *(u32*)(sOT + col * 128 + ((j ^ (col & 7)) * 16) + quad * 4) = pk;
        }
      }
      __syncthreads();
      int ch = pass * 256 + tid;   // 0..511
      unsigned char* vb = Vct + (size_t)b * 2097152 + (size_t)ch * 8;
      #pragma unroll
      for (int j = 0; j < 8; ++j) {
        u32x4 val = *(const u32x4*)(sOT + tid * 128 + ((j ^ (tid & 7)) * 16));
        int ktile = ktbase + (j >> 2);
        int ks = (j >> 1) & 1;
        int q0 = (j & 1) * 2;                       // 16B chunk = quads q0, q0+1
        unsigned char* basep = vb + (size_t)((ktile * 2 + ks) * 4 + q0) * 4096;
        u32x2 lo; lo.x = val.x; lo.y = val.y;
        u32x2 hi; hi.x = val.z; hi.y = val.w;
        *(u32x2*)(basep) = lo;
        *(u32x2*)(basep + 4096) = hi;
      }
      __syncthreads();
    }
  }
}

// ---------------- flash fused (VERIFIED Round-7 path): q-tile 32, all 64 kt, writes out ----------------
__global__ __launch_bounds__(512, 4) void flash_fused(
    const unsigned char* __restrict__ Qn,
    const unsigned char* __restrict__ Kn,
    const unsigned char* __restrict__ Vct,     // [b][kt][ks][quad][512ch][8] fp8 tiles
    const float* __restrict__ content,
    const float* __restrict__ stats,
    float* __restrict__ out) {
  // layout: sK 2x16K | sP 2x2K | sL 128B; epilogue overlays f32 sE2[256][32] on sK
  __shared__ __align__(16) char smem[32768 + 4096 + 128];
  char* sKb = smem;
  char* sPb = smem + 32768;
  float* sL = (float*)(smem + 36864);
  float* sE2 = (float*)smem;

  int tid = threadIdx.x;
  int wid = tid >> 6, lane = tid & 63, quad = lane >> 4, l16 = lane & 15;
  int uwid = __builtin_amdgcn_readfirstlane(wid);

  int id = blockIdx.x;                       // 512 blocks; XCD swizzle: batch b on XCDs {2b,2b+1}
  int b = (id >> 1) & 3;
  int tile = ((id >> 3) << 1) | (id & 1);    // 0..127
  int q0 = tile * 32;

  int qh = (wid >> 2) * 16;        // S-phase q half (16 q per wave)
  int kb0 = (wid & 3) * 16;        // S-phase key stripe (16 keys)
  int cw = wid * 64;               // PV ch base (64 of 512)

  long qf[8];
  {
    int row = q0 + qh + l16;
    const unsigned char* base = Qn + (((size_t)b * NN + row) << 8);
    #pragma unroll
    for (int kf = 0; kf < 8; ++kf)
      qf[kf] = *(const long*)(base + kf * 32 + quad * 8);
  }
  __builtin_amdgcn_s_waitcnt(WAITCNT(0, 7, 15));

  if (tid < 32) sL[tid] = 0.f;

  const unsigned char* kbp = Kn + (((size_t)b * NN) << 8);
  const unsigned char* vbp = Vct + (size_t)b * 2097152 + quad * 4096 + (size_t)(cw + l16) * 8;

  auto stageK = [&](int k0, int buf) {
    char* dst = sKb + buf * 16384;
    #pragma unroll
    for (int it = 0; it < 2; ++it) {
      int L = it * 512 + wid * 64 + lane;
      int ky = L >> 4, s = L & 15;
      int c16 = s ^ (ky & 15);
      async_cp16(kbp + (((size_t)(k0 + ky)) << 8) + c16 * 16,
                 dst + (size_t)(it * 512 + uwid * 64) * 16);
    }
  };

  f32x4 zero4 = {0.f, 0.f, 0.f, 0.f};
  f32x4 om[2][4];
  #pragma unroll
  for (int i = 0; i < 2; ++i)
    #pragma unroll
    for (int j = 0; j < 4; ++j) om[i][j] = zero4;
  float Lr = 0.f;
  long vf[2][4];

  int krow = kb0 + l16;
  int krowoff = krow * 256;
  int khalf = (quad & 1) * 8;

  auto s_phase = [&](int kt) {
    const char* sKc = sKb + (kt & 1) * 16384;
    char* sPc = sPb + (kt & 1) * 2048;
    f32x4 ta = zero4, tb = zero4;
    #pragma unroll
    for (int kf = 0; kf < 8; kf += 2) {
      int sa = (kf * 2 + (quad >> 1)) ^ (krow & 15);
      long aka = *(const long*)(sKc + krowoff + sa * 16 + khalf);
      ta = MFMA_FP8(aka, qf[kf], ta);
      int sb = ((kf + 1) * 2 + (quad >> 1)) ^ (krow & 15);
      long akb = *(const long*)(sKc + krowoff + sb * 16 + khalf);
      tb = MFMA_FP8(akb, qf[kf + 1], tb);
    }
    f32x4 sv = ta + tb;
    float p0 = __expf(sv.x), p1 = __expf(sv.y), p2 = __expf(sv.z), p3 = __expf(sv.w);
    Lr += p0 + p1 + p2 + p3;
    u32 w = pk4_fp8(p0, p1, p2, p3);
    int q = qh + l16;
    int c = (kb0 >> 2) + quad;
    *(u32*)(sPc + q * 64 + ((c ^ (q & 14)) * 4)) = w;
    const unsigned char* vt = vbp + (size_t)kt * 32768;
    #pragma unroll
    for (int ks = 0; ks < 2; ++ks)
      #pragma unroll
      for (int nf = 0; nf < 4; ++nf)
        vf[ks][nf] = *(const long*)(vt + ks * 16384 + nf * 128);
  };

  stageK(0, 0);  stageK(64, 1);
  __builtin_amdgcn_s_waitcnt(WAITCNT(2, 7, 15));
  __builtin_amdgcn_s_barrier();
  s_phase(0);
  __builtin_amdgcn_s_waitcnt(WAITCNT(63, 7, 0));
  __builtin_amdgcn_s_barrier();

  for (int kt = 0; kt < 64; ++kt) {
    stageK(((kt + 2) & 63) * 64, kt & 1);
    __builtin_amdgcn_s_waitcnt(WAITCNT(2, 7, 15));

    const char* sPc = sPb + (kt & 1) * 2048;
    long pf[2][2];
    #pragma unroll
    for (int ks = 0; ks < 2; ++ks)
      #pragma unroll
      for (int mf = 0; mf < 2; ++mf) {
        int q = mf * 16 + l16;
        int c = ks * 8 + quad * 2;
        pf[ks][mf] = *(const long*)(sPc + q * 64 + ((c ^ (q & 14)) * 4));
      }

    #pragma unroll
    for (int ks = 0; ks < 2; ++ks)
      #pragma unroll
      for (int nf = 0; nf < 4; ++nf)
        #pragma unroll
        for (int mf = 0; mf < 2; ++mf)
          om[mf][nf] = MFMA_FP8(pf[ks][mf], vf[ks][nf], om[mf][nf]);

    if (kt < 63) s_phase(kt + 1);

    __builtin_amdgcn_s_waitcnt(WAITCNT(63, 7, 0));
    __builtin_amdgcn_s_barrier();
  }

  Lr += __shfl_xor(Lr, 16, 64);
  Lr += __shfl_xor(Lr, 32, 64);
  if (quad == 0) atomicAdd(&sL[qh + l16], Lr);
  __builtin_amdgcn_s_waitcnt(WAITCNT(0, 7, 0));
  __builtin_amdgcn_s_barrier();

  if (wid >= 4) {
    #pragma unroll
    for (int mf = 0; mf < 2; ++mf) {
      #pragma unroll
      for (int nf = 0; nf < 4; ++nf) {
        int ch = (wid - 4) * 64 + nf * 16 + l16;
        int cidx = (mf * 4 + quad) ^ (ch & 7);
        *(f32x4*)(sE2 + ch * 32 + cidx * 4) = om[mf][nf];
      }
    }
  }
  __syncthreads();

  if (wid < 4) {
    const float* meanc = stats + (0 * BB + b) * CC;
    const float* rstdc = stats + (1 * BB + b) * CC;
    float linv[2][4];
    #pragma unroll
    for (int mf = 0; mf < 2; ++mf)
      #pragma unroll
      for (int r = 0; r < 4; ++r)
        linv[mf][r] = 1.0f / sL[mf * 16 + quad * 4 + r];
    #pragma unroll
    for (int nf = 0; nf < 4; ++nf) {
      int ch = cw + nf * 16 + l16;
      float mc = meanc[ch], rc = rstdc[ch];
      #pragma unroll
      for (int mf = 0; mf < 2; ++mf) {
        int cidx = (mf * 4 + quad) ^ (ch & 7);
        f32x4 vv = *(const f32x4*)(sE2 + ch * 32 + cidx * 4);
        f32x4 ov = om[mf][nf];
        #pragma unroll
        for (int r = 0; r < 4; ++r) {
          int row = mf * 16 + quad * 4 + r;
          float li = linv[mf][r];
          float ovr = (r == 0) ? ov.x : (r == 1) ? ov.y : (r == 2) ? ov.z : ov.w;
          float vvr = (r == 0) ? vv.x : (r == 1) ? vv.y : (r == 2) ? vv.z : vv.w;
          float M = ovr * li;
          float E2 = vvr * li;
          float S2 = E2 - M * M;
          float S = (S2 > 0.f) ? sqrtf(S2) : 0.f;
          size_t gi = (((size_t)b * NN + q0 + row) << 8) + ch;
          float xh = (content[gi] - mc) * rc;
          out[gi] = S * xh + M;
        }
      }
    }
  }
}

// ---------------- flash split: q-tile 32, kt-split x2, 4 blocks/CU, writes f32 partials ----------------
__global__ __launch_bounds__(512, 8) void flash_split(
    const unsigned char* __restrict__ Qn,
    const unsigned char* __restrict__ Kn,
    const unsigned char* __restrict__ Vct,     // [b][kt][ks][quad][512ch][8] fp8 tiles
    float* __restrict__ gOM,                   // [tb2 = (b*128+tile)*2+kh][32 q][512 ch] f32
    float* __restrict__ gL) {                  // [tb2][32 q] f32
  // layout: sK 2x16K | sP 2x2K | sL 128B
  __shared__ __align__(16) char smem[32768 + 4096 + 128];
  char* sKb = smem;
  char* sPb = smem + 32768;
  float* sL = (float*)(smem + 36864);

  int tid = threadIdx.x;
  int wid = tid >> 6, lane = tid & 63, quad = lane >> 4, l16 = lane & 15;
  int uwid = __builtin_amdgcn_readfirstlane(wid);

  int id = blockIdx.x;                       // 1024; batch b pinned to XCD pair {2b,2b+1}
  int kh = id >> 9;                          // key-half 0/1
  int b = (id >> 1) & 3;
  int tile = (((id & 511) >> 3) << 1) | (id & 1);    // 0..127 within batch
  int q0 = tile * 32;
  int kt0 = kh << 5;                         // 0 or 32

  int qh = (wid >> 2) * 16;        // S-phase q half (16 q per wave)
  int kb0 = (wid & 3) * 16;        // S-phase key stripe (16 keys)
  int cw = wid * 64;               // PV ch base (64 of 512)

  long qf[8];
  {
    int row = q0 + qh + l16;
    const unsigned char* base = Qn + (((size_t)b * NN + row) << 8);
    #pragma unroll
    for (int kf = 0; kf < 8; ++kf)
      qf[kf] = *(const long*)(base + kf * 32 + quad * 8);
  }
  __builtin_amdgcn_s_waitcnt(WAITCNT(0, 7, 15));

  if (tid < 32) sL[tid] = 0.f;

  const unsigned char* kbp = Kn + (((size_t)b * NN) << 8);
  const unsigned char* vbp = Vct + (size_t)b * 2097152 + quad * 4096 + (size_t)(cw + l16) * 8;

  auto stageK = [&](int k0, int buf) {
    char* dst = sKb + buf * 16384;
    #pragma unroll
    for (int it = 0; it < 2; ++it) {
      int L = it * 512 + wid * 64 + lane;
      int ky = L >> 4, s = L & 15;
      int c16 = s ^ (ky & 15);
      async_cp16(kbp + (((size_t)(k0 + ky)) << 8) + c16 * 16,
                 dst + (size_t)(it * 512 + uwid * 64) * 16);
    }
  };

  f32x4 zero4 = {0.f, 0.f, 0.f, 0.f};
  f32x4 om[2][4];
  #pragma unroll
  for (int i = 0; i < 2; ++i)
    #pragma unroll
    for (int j = 0; j < 4; ++j) om[i][j] = zero4;
  float Lr = 0.f;
  long vf[2][4];

  int krow = kb0 + l16;
  int krowoff = krow * 256;
  int khalf = (quad & 1) * 8;

  auto s_phase = [&](int kt) {
    const char* sKc = sKb + (kt & 1) * 16384;
    char* sPc = sPb + (kt & 1) * 2048;
    f32x4 ta = zero4, tb = zero4;
    #pragma unroll
    for (int kf = 0; kf < 8; kf += 2) {
      int sa = (kf * 2 + (quad >> 1)) ^ (krow & 15);
      long aka = *(const long*)(sKc + krowoff + sa * 16 + khalf);
      ta = MFMA_FP8(aka, qf[kf], ta);
      int sb = ((kf + 1) * 2 + (quad >> 1)) ^ (krow & 15);
      long akb = *(const long*)(sKc + krowoff + sb * 16 + khalf);
      tb = MFMA_FP8(akb, qf[kf + 1], tb);
    }
    f32x4 sv = ta + tb;
    float p0 = __expf(sv.x), p1 = __expf(sv.y), p2 = __expf(sv.z), p3 = __expf(sv.w);
    Lr += p0 + p1 + p2 + p3;
    u32 w = pk4_fp8(p0, p1, p2, p3);
    int q = qh + l16;
    int c = (kb0 >> 2) + quad;
    *(u32*)(sPc + q * 64 + ((c ^ (q & 14)) * 4)) = w;
    const unsigned char* vt = vbp + (size_t)kt * 32768;
    #pragma unroll
    for (int ks = 0; ks < 2; ++ks)
      #pragma unroll
      for (int nf = 0; nf < 4; ++nf)
        vf[ks][nf] = *(const long*)(vt + ks * 16384 + nf * 128);
  };

  stageK(kt0 * 64, 0);  stageK((kt0 + 1) * 64, 1);
  __builtin_amdgcn_s_waitcnt(WAITCNT(2, 7, 15));
  __builtin_amdgcn_s_barrier();
  s_phase(kt0);
  __builtin_amdgcn_s_waitcnt(WAITCNT(63, 7, 0));
  __builtin_amdgcn_s_barrier();

  for (int i = 0; i < 32; ++i) {
    int kt = kt0 + i;
    stageK(((kt + 2) & 63) * 64, kt & 1);
    __builtin_amdgcn_s_waitcnt(WAITCNT(2, 7, 15));

    const char* sPc = sPb + (kt & 1) * 2048;
    long pf[2][2];
    #pragma unroll
    for (int ks = 0; ks < 2; ++ks)
      #pragma unroll
      for (int mf = 0; mf < 2; ++mf) {
        int q = mf * 16 + l16;
        int c = ks * 8 + quad * 2;
        pf[ks][mf] = *(const long*)(sPc + q * 64 + ((c ^ (q & 14)) * 4));
      }

    #pragma unroll
    for (int ks = 0; ks < 2; ++ks)
      #pragma unroll
      for (int nf = 0; nf < 4; ++nf)
        #pragma unroll
        for (int mf = 0; mf < 2; ++mf)
          om[mf][nf] = MFMA_FP8(pf[ks][mf], vf[ks][nf], om[mf][nf]);

    if (i < 31) s_phase(kt + 1);

    __builtin_amdgcn_s_waitcnt(WAITCNT(63, 7, 0));
    __builtin_amdgcn_s_barrier();
  }

  Lr += __shfl_xor(Lr, 16, 64);
  Lr += __shfl_xor(Lr, 32, 64);
  if (quad == 0) atomicAdd(&sL[qh + l16], Lr);
  __builtin_amdgcn_s_waitcnt(WAITCNT(0, 7, 0));   // drain dead K prefetch + publish sL
  __builtin_amdgcn_s_barrier();

  // ---- write partials: gL (32 f32) and gOM ([32 q][512 ch] f32), coalesced 64B segments ----
  int tb2 = (b * 128 + tile) * 2 + kh;
  if (tid < 32) gL[tb2 * 32 + tid] = sL[tid];
  float* gb = gOM + (size_t)tb2 * (32 * 512);
  #pragma unroll
  for (int mf = 0; mf < 2; ++mf) {
    int qrow = mf * 16 + quad * 4;
    #pragma unroll
    for (int nf = 0; nf < 4; ++nf) {
      int ch = cw + nf * 16 + l16;
      f32x4 v = om[mf][nf];
      gb[(size_t)(qrow + 0) * 512 + ch] = v.x;
      gb[(size_t)(qrow + 1) * 512 + ch] = v.y;
      gb[(size_t)(qrow + 2) * 512 + ch] = v.z;
      gb[(size_t)(qrow + 3) * 512 + ch] = v.w;
    }
  }
}

// ---------------- reduce: combine kt-halves, normalize, instance-norm content, output ----------------
// grid (512, 2) x 256 thr: block (bx, qh2) handles tile bx (= b*128+tile), q rows qh2*16..+15.
__global__ __launch_bounds__(256) void reduce_kernel(
    const float* __restrict__ gOM, const float* __restrict__ gL,
    const float* __restrict__ content, const float* __restrict__ stats,
    float* __restrict__ out) {
  int bx = blockIdx.x;          // 0..511 = b*128 + tile
  int qh2 = blockIdx.y;         // 0/1
  int b = bx >> 7, tile = bx & 127;
  int t = threadIdx.x;          // ch 0..255
  __shared__ float sLr[32];
  if (t < 32) sLr[t] = gL[(bx * 2 + 0) * 32 + t] + gL[(bx * 2 + 1) * 32 + t];
  __syncthreads();
  float mc = stats[(0 * BB + b) * CC + t];    // content mean
  float rc = stats[(1 * BB + b) * CC + t];    // content rstd
  const float* g0 = gOM + (size_t)(bx * 2 + 0) * (32 * 512);
  const float* g1 = gOM + (size_t)(bx * 2 + 1) * (32 * 512);
  #pragma unroll 4
  for (int qq = 0; qq < 16; ++qq) {
    int q = qh2 * 16 + qq;
    float li = 1.0f / sLr[q];
    float M  = (g0[(size_t)q * 512 + t]       + g1[(size_t)q * 512 + t])       * li;
    float E2 = (g0[(size_t)q * 512 + 256 + t] + g1[(size_t)q * 512 + 256 + t]) * li;
    float S2 = E2 - M * M;
    float S = (S2 > 0.f) ? sqrtf(S2) : 0.f;
    size_t gi = (((size_t)b * NN + tile * 32 + q) << 8) + t;
    float xh = (content[gi] - mc) * rc;
    out[gi] = S * xh + M;
  }
}

// ---------------- launcher ----------------
extern "C" void kernel_launch(void* const* d_in, const int* in_sizes, int n_in,
                              void* d_out, int out_size, void* d_ws, size_t ws_size,
                              hipStream_t stream) {
  const float* content = (const float*)d_in[0];
  const float* style   = (const float*)d_in[1];
  const float* Wq = (const float*)d_in[2];
  const float* bq = (const float*)d_in[3];
  const float* Wk = (const float*)d_in[4];
  const float* bk = (const float*)d_in[5];
  const float* Wv = (const float*)d_in[6];
  const float* bv = (const float*)d_in[7];
  char* ws = (char*)d_ws;

  float* sums        = (float*)(ws + 0);                 // 16 KB
  float* stats       = (float*)(ws + 16384);             // 16 KB
  unsigned char* Wt8 = (unsigned char*)(ws + 32768);     // 192 KB fp8 [3][256][256]
  unsigned char* Qn  = (unsigned char*)(ws + 229376);    // 4 MB fp8
  unsigned char* Kn  = (unsigned char*)(ws + 4423680);   // 4 MB fp8
  unsigned char* Vct = (unsigned char*)(ws + 8617984);   // 8 MB fp8 tiled [b][kt][ks][quad][512][8]
  float* gL          = (float*)(ws + 17006592);          // 128 KB f32 partial L  [1024][32]
  float* gOM         = (float*)(ws + 17137664);          // 64 MB f32 partial OM [1024][32][512]
  const size_t WS_NEED = 17137664ull + 67108864ull;      // = 84,246,528
  float* outp = (float*)d_out;

  hipMemsetAsync(d_ws, 0, 16384, stream);
  hipLaunchKernelGGL(transpose_w, dim3(48), dim3(256), 0, stream, Wq, Wk, Wv, Wt8);
  hipLaunchKernelGGL(stats_partial, dim3(1024), dim3(256), 0, stream, content, style, sums);
  hipLaunchKernelGGL(stats_finalize, dim3(8), dim3(256), 0, stream, sums, stats);
  hipLaunchKernelGGL(qkv_kernel, dim3(128, 3), dim3(256), 0, stream,
                     content, style, Wt8, bq, bk, bv, stats, Qn, Kn, Vct);
  if (ws_size >= WS_NEED) {
    hipLaunchKernelGGL(flash_split, dim3(1024), dim3(512), 0, stream,
                       Qn, Kn, Vct, gOM, gL);
    hipLaunchKernelGGL(reduce_kernel, dim3(512, 2), dim3(256), 0, stream,
                       gOM, gL, content, stats, outp);
  } else {
    hipLaunchKernelGGL(flash_fused, dim3(512), dim3(512), 0, stream,
                       Qn, Kn, Vct, content, stats, outp);
  }
}

// Round 17
// 219.719 us; speedup vs baseline: 1.9560x; 1.9560x over previous
//
#include <hip/hip_runtime.h>
#include <cstdint>

#define BB 4
#define NN 4096
#define CC 256

typedef __attribute__((ext_vector_type(8))) short bf16x8;
typedef __attribute__((ext_vector_type(4))) short bf16x4;
typedef __attribute__((ext_vector_type(4))) float f32x4;
typedef unsigned int u32;
typedef __attribute__((ext_vector_type(4))) u32 u32x4;
typedef __attribute__((ext_vector_type(2))) u32 u32x2;

#define MFMA_FP8(a, b, c)  __builtin_amdgcn_mfma_f32_16x16x32_fp8_fp8((a), (b), (c), 0, 0, 0)

// gfx9 s_waitcnt immediate: vmcnt[3:0]+[15:14], expcnt[6:4], lgkmcnt[11:8]
#define WAITCNT(vm, xp, lgkm) (((vm) & 0xF) | (((vm) >> 4) << 14) | ((xp) << 4) | ((lgkm) << 8))

__device__ __forceinline__ unsigned short f2bf(float f) {
  union { float f; unsigned u; } v; v.f = f;
  unsigned r = v.u + 0x7fffu + ((v.u >> 16) & 1u);
  return (unsigned short)(r >> 16);
}
// pack 4 f32 -> 4 fp8 e4m3 (OCP) in one dword, byte order a,b,c,d
__device__ __forceinline__ u32 pk4_fp8(float a, float b, float c, float d) {
  u32 v = (u32)__builtin_amdgcn_cvt_pk_fp8_f32(a, b, 0, false);
  v = (u32)__builtin_amdgcn_cvt_pk_fp8_f32(c, d, (int)v, true);
  return v;
}
__device__ __forceinline__ unsigned char fp8_1(float a) {
  return (unsigned char)(((u32)__builtin_amdgcn_cvt_pk_fp8_f32(a, a, 0, false)) & 0xff);
}

typedef __attribute__((address_space(3))) unsigned int lds_u32;
typedef __attribute__((address_space(1))) unsigned int glb_u32;

// async global->LDS, 16B per lane; LDS dest = wave-uniform base + lane*16
__device__ __forceinline__ void async_cp16(const void* g, void* l) {
  __builtin_amdgcn_global_load_lds((const glb_u32*)g,
                                   (lds_u32*)(unsigned)(unsigned long long)l,
                                   16, 0, 0);
}

// ---------------- prep: fused {stats_partial | W-transpose} (independent work, one launch) ----------------
// blocks [0,1024): instance-norm partial sums; blocks [1024,1072): Wt8[z][d][c] = fp8(W_z[c][d])
__global__ __launch_bounds__(256) void prep_kernel(const float* __restrict__ content,
                                                   const float* __restrict__ style,
                                                   const float* __restrict__ Wq,
                                                   const float* __restrict__ Wk,
                                                   const float* __restrict__ Wv,
                                                   float* __restrict__ sums,
                                                   unsigned char* __restrict__ Wt8) {
  __shared__ float sT[64 * 65];
  int gblk = blockIdx.x;
  if (gblk < 1024) {
    int t = gblk >> 9, b = (gblk >> 7) & 3, chunk = gblk & 127;
    const float* X = t ? style : content;
    int c = threadIdx.x;
    const float* base = X + ((size_t)b * NN + (size_t)chunk * 32) * CC + c;
    float s = 0.f, ss = 0.f;
    #pragma unroll 8
    for (int r = 0; r < 32; ++r) {
      float x = base[(size_t)r * CC];
      s += x; ss += x * x;
    }
    atomicAdd(&sums[((t * 2 + 0) * BB + b) * CC + c], s);
    atomicAdd(&sums[((t * 2 + 1) * BB + b) * CC + c], ss);
  } else {
    int blk = gblk - 1024;           // 48 = 3 * 16
    int z = blk / 16, tl = blk % 16;
    int c0 = (tl >> 2) * 64, d0 = (tl & 3) * 64;
    const float* W = (z == 0) ? Wq : ((z == 1) ? Wk : Wv);
    #pragma unroll
    for (int i = 0; i < 16; ++i) {
      int e = i * 256 + threadIdx.x;
      int c = e >> 6, d = e & 63;
      sT[c * 65 + d] = W[(size_t)(c0 + c) * CC + d0 + d];
    }
    __syncthreads();
    #pragma unroll
    for (int i = 0; i < 16; ++i) {
      int e = i * 256 + threadIdx.x;
      int d = e >> 6, c = e & 63;
      Wt8[(size_t)z * 65536 + (size_t)(d0 + d) * CC + c0 + c] = fp8_1(sT[c * 65 + d]);
    }
  }
}

__global__ __launch_bounds__(256) void stats_finalize(const float* __restrict__ sums,
                                                      float* __restrict__ stats) {
  int i = blockIdx.x * 256 + threadIdx.x;   // 2048 = 2*B*C
  int t = i >> 10, bc = i & 1023;
  float s = sums[(t * 2 + 0) * 1024 + bc];
  float ss = sums[(t * 2 + 1) * 1024 + bc];
  float m = s * (1.0f / NN);
  float var = ss * (1.0f / NN) - m * m;
  stats[(t * 2 + 0) * 1024 + bc] = m;
  stats[(t * 2 + 1) * 1024 + bc] = rsqrtf(var + 1e-5f);
}

// ---------------- QKV: fp8 GEMM, 128-row x 256-col tiles, 256 thr, 2 blocks/CU ----------------
// Vct output layout (flash-read-optimal tiles):
//   Vct[b][ktile:64][ks:2][quad:4][ch:512][key8:8] fp8, 2 MB per batch.
//   key within 64-key tile = ks*32 + quad*8 + key8; ch<256: V, ch>=256: V^2.
__global__ __launch_bounds__(256, 2) void qkv_kernel(
    const float* __restrict__ content, const float* __restrict__ style,
    const unsigned char* __restrict__ Wt8,
    const float* __restrict__ bq, const float* __restrict__ bk, const float* __restrict__ bv,
    const float* __restrict__ stats,
    unsigned char* __restrict__ Qn, unsigned char* __restrict__ Kn,
    unsigned char* __restrict__ Vct) {
  __shared__ __align__(16) char sW[32768];   // [256 d][128 c] fp8, slot8 = c16 ^ (d&7)
  __shared__ __align__(16) char sX[32768];   // [128 r][256 c] fp8, slot16 = c16 ^ (r&15); V-epilogue alias sOT[256][128]

  int tid = threadIdx.x;
  int wid = tid >> 6, lane = tid & 63, quad = lane >> 4, l16 = lane & 15;
  int uwid = __builtin_amdgcn_readfirstlane(wid);
  int tileid = blockIdx.x;      // 0..127 over B*N/128
  int z = blockIdx.y;           // 0=Q 1=K 2=V
  int gr0 = tileid * 128;       // global row over B*N
  int b = gr0 >> 12;

  const float* X = (z == 0) ? content : style;
  int statt = (z == 0) ? 0 : 1;
  const float* mean = stats + ((statt * 2 + 0) * BB + b) * CC;
  const float* rstd = stats + ((statt * 2 + 1) * BB + b) * CC;
  bool donorm = (z < 2);

  // ---- stage sX: x-hat (or raw style for V) quantized to fp8, swizzled ----
  #pragma unroll
  for (int i = 0; i < 8; ++i) {
    int lin = i * 256 + tid;
    int row = lin >> 4, c16 = lin & 15;
    int c = c16 * 16;
    const float* xr = X + (size_t)(gr0 + row) * CC + c;
    f32x4 x0 = *(const f32x4*)(xr + 0);
    f32x4 x1 = *(const f32x4*)(xr + 4);
    f32x4 x2 = *(const f32x4*)(xr + 8);
    f32x4 x3 = *(const f32x4*)(xr + 12);
    if (donorm) {
      f32x4 m0 = *(const f32x4*)(mean + c + 0), r0 = *(const f32x4*)(rstd + c + 0);
      f32x4 m1 = *(const f32x4*)(mean + c + 4), r1 = *(const f32x4*)(rstd + c + 4);
      f32x4 m2 = *(const f32x4*)(mean + c + 8), r2 = *(const f32x4*)(rstd + c + 8);
      f32x4 m3 = *(const f32x4*)(mean + c + 12), r3 = *(const f32x4*)(rstd + c + 12);
      x0 = (x0 - m0) * r0; x1 = (x1 - m1) * r1;
      x2 = (x2 - m2) * r2; x3 = (x3 - m3) * r3;
    }
    u32x4 pk;
    pk.x = pk4_fp8(x0.x, x0.y, x0.z, x0.w);
    pk.y = pk4_fp8(x1.x, x1.y, x1.z, x1.w);
    pk.z = pk4_fp8(x2.x, x2.y, x2.z, x2.w);
    pk.w = pk4_fp8(x3.x, x3.y, x3.z, x3.w);
    *(u32x4*)(sX + row * 256 + ((c16 ^ (row & 15)) * 16)) = pk;
  }

  f32x4 zero4 = {0.f, 0.f, 0.f, 0.f};
  f32x4 acc[2][16];
  #pragma unroll
  for (int i = 0; i < 2; ++i)
    #pragma unroll
    for (int j = 0; j < 16; ++j) acc[i][j] = zero4;

  const unsigned char* wb = Wt8 + (size_t)z * 65536;

  for (int half = 0; half < 2; ++half) {
    __syncthreads();   // sX visible (half0) / sW reads of prior half done (half1)
    // stage sW half: [256 d][128 c] fp8 from Wt8[z][d][half*128+..]
    #pragma unroll
    for (int it = 0; it < 8; ++it) {
      int L = it * 256 + wid * 64 + lane;
      int d = L >> 3;
      int c16 = (L & 7) ^ (d & 7);
      async_cp16(wb + (size_t)d * 256 + half * 128 + c16 * 16,
                 sW + (size_t)(it * 256 + uwid * 64) * 16);
    }
    __syncthreads();   // drain (compiler emits vmcnt(0) before barrier)

    // A-frags: rows wid*32 + mf*16 + l16, k-chunks kc*32 + quad*8 within this half
    long a[2][4];
    #pragma unroll
    for (int mf = 0; mf < 2; ++mf) {
      int row = wid * 32 + mf * 16 + l16;
      #pragma unroll
      for (int kc = 0; kc < 4; ++kc) {
        int chunk = half * 8 + kc * 2 + (quad >> 1);
        a[mf][kc] = *(const long*)(sX + row * 256 + ((chunk ^ (row & 15)) * 16) + (quad & 1) * 8);
      }
    }
    #pragma unroll
    for (int nf = 0; nf < 16; ++nf) {
      int d = nf * 16 + l16;
      #pragma unroll
      for (int kc = 0; kc < 4; ++kc) {
        long bw = *(const long*)(sW + d * 128 + (((kc * 2 + (quad >> 1)) ^ (d & 7)) * 16) + (quad & 1) * 8);
        acc[0][nf] = MFMA_FP8(a[0][kc], bw, acc[0][nf]);
        acc[1][nf] = MFMA_FP8(a[1][kc], bw, acc[1][nf]);
      }
    }
  }

  // ---- bias (before l2norm / store) ----
  const float* bias = (z == 0) ? bq : ((z == 1) ? bk : bv);
  #pragma unroll
  for (int nf = 0; nf < 16; ++nf) {
    float bb_ = bias[nf * 16 + l16];
    #pragma unroll
    for (int mf = 0; mf < 2; ++mf) {
      acc[mf][nf].x += bb_; acc[mf][nf].y += bb_;
      acc[mf][nf].z += bb_; acc[mf][nf].w += bb_;
    }
  }

  if (z < 2) {
    // l2-normalize rows (sum over all 256 cols lives in this wave), store fp8 row-major
    unsigned char* O = (z == 0) ? Qn : Kn;
    #pragma unroll
    for (int mf = 0; mf < 2; ++mf) {
      f32x4 ss = zero4;
      #pragma unroll
      for (int nf = 0; nf < 16; ++nf) ss += acc[mf][nf] * acc[mf][nf];
      #pragma unroll
      for (int m = 1; m < 16; m <<= 1) {
        ss.x += __shfl_xor(ss.x, m, 64);
        ss.y += __shfl_xor(ss.y, m, 64);
        ss.z += __shfl_xor(ss.z, m, 64);
        ss.w += __shfl_xor(ss.w, m, 64);
      }
      f32x4 rq;
      rq.x = rsqrtf(ss.x + 1e-12f); rq.y = rsqrtf(ss.y + 1e-12f);
      rq.z = rsqrtf(ss.z + 1e-12f); rq.w = rsqrtf(ss.w + 1e-12f);
      int r0 = wid * 32 + mf * 16 + quad * 4;
      #pragma unroll
      for (int nf = 0; nf < 16; ++nf) {
        int col = nf * 16 + l16;
        u32 p01 = (u32)__builtin_amdgcn_cvt_pk_fp8_f32(acc[mf][nf].x * rq.x, acc[mf][nf].y * rq.y, 0, false);
        u32 p23 = (u32)__builtin_amdgcn_cvt_pk_fp8_f32(acc[mf][nf].z * rq.z, acc[mf][nf].w * rq.w, 0, false);
        O[(size_t)(gr0 + r0 + 0) * CC + col] = (unsigned char)(p01 & 0xff);
        O[(size_t)(gr0 + r0 + 1) * CC + col] = (unsigned char)((p01 >> 8) & 0xff);
        O[(size_t)(gr0 + r0 + 2) * CC + col] = (unsigned char)(p23 & 0xff);
        O[(size_t)(gr0 + r0 + 3) * CC + col] = (unsigned char)((p23 >> 8) & 0xff);
      }
    }
  } else {
    // V: two passes through sOT (alias sX): pass0 = V, pass1 = V^2.
    // Store to tiled Vct[b][ktile][ks][quad][ch][8]; 8B stores, ch-contiguous across threads.
    char* sOT = sX;   // [256 ch][128 row] fp8, chunk j' = j ^ (ch&7)
    int n_in_b = gr0 & (NN - 1);        // multiple of 128
    int ktbase = n_in_b >> 6;           // first of 2 ktiles covered by this 128-row window
    __syncthreads();   // all sX A-reads done
    #pragma unroll
    for (int pass = 0; pass < 2; ++pass) {
      #pragma unroll
      for (int mf = 0; mf < 2; ++mf) {
        int j = wid * 2 + mf;
        #pragma unroll
        for (int nf = 0; nf < 16; ++nf) {
          int col = nf * 16 + l16;
          f32x4 v = acc[mf][nf];
          f32x4 w = pass ? (v * v) : v;
          u32 pk = pk4_fp8(w.x, w.y, w.z, w.w);
          *(u32*)(sOT + col * 128 + ((j ^ (col & 7)) * 16) + quad * 4) = pk;
        }
      }
      __syncthreads();
      int ch = pass * 256 + tid;   // 0..511
      unsigned char* vb = Vct + (size_t)b * 2097152 + (size_t)ch * 8;
      #pragma unroll
      for (int j = 0; j < 8; ++j) {
        u32x4 val = *(const u32x4*)(sOT + tid * 128 + ((j ^ (tid & 7)) * 16));
        int ktile = ktbase + (j >> 2);
        int ks = (j >> 1) & 1;
        int q0 = (j & 1) * 2;                       // 16B chunk = quads q0, q0+1
        unsigned char* basep = vb + (size_t)((ktile * 2 + ks) * 4 + q0) * 4096;
        u32x2 lo; lo.x = val.x; lo.y = val.y;
        u32x2 hi; hi.x = val.z; hi.y = val.w;
        *(u32x2*)(basep) = lo;
        *(u32x2*)(basep + 4096) = hi;
      }
      __syncthreads();
    }
  }
}

// ---------------- flash attention (verified R7 structure + T5 setprio): q-tile 32, V direct ----------------
__global__ __launch_bounds__(512, 4) void flash_kernel(
    const unsigned char* __restrict__ Qn,
    const unsigned char* __restrict__ Kn,
    const unsigned char* __restrict__ Vct,     // [b][kt][ks][quad][512ch][8] fp8 tiles
    const float* __restrict__ content,
    const float* __restrict__ stats,
    float* __restrict__ out) {
  // layout: sK 2x16K | sP 2x2K | sL 128B; epilogue overlays f32 sE2[256][32] on sK
  __shared__ __align__(16) char smem[32768 + 4096 + 128];
  char* sKb = smem;
  char* sPb = smem + 32768;
  float* sL = (float*)(smem + 36864);
  float* sE2 = (float*)smem;

  int tid = threadIdx.x;
  int wid = tid >> 6, lane = tid & 63, quad = lane >> 4, l16 = lane & 15;
  int uwid = __builtin_amdgcn_readfirstlane(wid);

  int id = blockIdx.x;                       // 512 blocks; XCD swizzle: batch b on XCDs {2b,2b+1}
  int b = (id >> 1) & 3;
  int tile = ((id >> 3) << 1) | (id & 1);    // 0..127
  int q0 = tile * 32;

  int qh = (wid >> 2) * 16;        // S-phase q half (16 q per wave)
  int kb0 = (wid & 3) * 16;        // S-phase key stripe (16 keys)
  int cw = wid * 64;               // PV ch base (64 of 512)

  // Q B-frags fp8 in registers: lane holds Q[q = qh+l16][k = kf*32+quad*8..+7]
  long qf[8];
  {
    int row = q0 + qh + l16;
    const unsigned char* base = Qn + (((size_t)b * NN + row) << 8);
    #pragma unroll
    for (int kf = 0; kf < 8; ++kf)
      qf[kf] = *(const long*)(base + kf * 32 + quad * 8);
  }
  __builtin_amdgcn_s_waitcnt(WAITCNT(0, 7, 15));   // drain qf: loop vmcnt counts staging+vf only

  if (tid < 32) sL[tid] = 0.f;

  const unsigned char* kbp = Kn + (((size_t)b * NN) << 8);
  // V: per-lane base offset within a 32KB kt-tile: + ks*16384 + nf*128 later
  const unsigned char* vbp = Vct + (size_t)b * 2097152 + quad * 4096 + (size_t)(cw + l16) * 8;

  // K tile [64 key][256 c] fp8 = 16 KB; 16B chunks swizzled: slot = c16 ^ (key&15)
  auto stageK = [&](int k0, int buf) {
    char* dst = sKb + buf * 16384;
    #pragma unroll
    for (int it = 0; it < 2; ++it) {
      int L = it * 512 + wid * 64 + lane;
      int ky = L >> 4, s = L & 15;
      int c16 = s ^ (ky & 15);
      async_cp16(kbp + (((size_t)(k0 + ky)) << 8) + c16 * 16,
                 dst + (size_t)(it * 512 + uwid * 64) * 16);
    }
  };

  f32x4 zero4 = {0.f, 0.f, 0.f, 0.f};
  f32x4 om[2][4];
  #pragma unroll
  for (int i = 0; i < 2; ++i)
    #pragma unroll
    for (int j = 0; j < 4; ++j) om[i][j] = zero4;
  float Lr = 0.f;
  long vf[2][4];    // V fragments for tile kt, global-loaded during s_phase(kt)

  int krow = kb0 + l16;
  int krowoff = krow * 256;
  int khalf = (quad & 1) * 8;

  // S^T(kt) + exp + sP(kt) write + issue vf(kt) global loads (consumed by PV(kt) next iter)
  auto s_phase = [&](int kt) {
    const char* sKc = sKb + (kt & 1) * 16384;
    char* sPc = sPb + (kt & 1) * 2048;
    f32x4 ta = zero4, tb = zero4;     // ILP-2 split of the 8-deep K-chain
    __builtin_amdgcn_s_setprio(1);
    #pragma unroll
    for (int kf = 0; kf < 8; kf += 2) {
      int sa = (kf * 2 + (quad >> 1)) ^ (krow & 15);
      long aka = *(const long*)(sKc + krowoff + sa * 16 + khalf);
      ta = MFMA_FP8(aka, qf[kf], ta);     // D[key][q], keys quad*4+reg, q=l16
      int sb = ((kf + 1) * 2 + (quad >> 1)) ^ (krow & 15);
      long akb = *(const long*)(sKc + krowoff + sb * 16 + khalf);
      tb = MFMA_FP8(akb, qf[kf + 1], tb);
    }
    __builtin_amdgcn_s_setprio(0);
    f32x4 sv = ta + tb;
    float p0 = __expf(sv.x), p1 = __expf(sv.y), p2 = __expf(sv.z), p3 = __expf(sv.w);
    Lr += p0 + p1 + p2 + p3;          // sum over this lane's 4 keys for q
    u32 w = pk4_fp8(p0, p1, p2, p3);  // bytes = keys (kb0+quad*4)+0..3
    int q = qh + l16;
    int c = (kb0 >> 2) + quad;        // 4B-chunk = key/4
    *(u32*)(sPc + q * 64 + ((c ^ (q & 14)) * 4)) = w;
    // issue vf(kt): 8 x global b64, 128B-contiguous per 16-lane group (L2-resident)
    const unsigned char* vt = vbp + (size_t)kt * 32768;
    #pragma unroll
    for (int ks = 0; ks < 2; ++ks)
      #pragma unroll
      for (int nf = 0; nf < 4; ++nf)
        vf[ks][nf] = *(const long*)(vt + ks * 16384 + nf * 128);
  };

  // prologue: K 2-deep; S(0) + sP(0) + vf(0) issue; publish
  stageK(0, 0);  stageK(64, 1);
  __builtin_amdgcn_s_waitcnt(WAITCNT(2, 7, 15));   // K(0) landed; K(1) in flight
  __builtin_amdgcn_s_barrier();
  s_phase(0);
  __builtin_amdgcn_s_waitcnt(WAITCNT(63, 7, 0));   // sP(0) + own LDS reads done
  __builtin_amdgcn_s_barrier();

  for (int kt = 0; kt < 64; ++kt) {
    // stage K(kt+2) into buf (kt&1)
    stageK(((kt + 2) & 63) * 64, kt & 1);    // wrap: dead prefetch on last iters, drained in epilogue

    // vf(kt) + K(kt+1) landed (2 newest outstanding = K(kt+2)'s staging)
    __builtin_amdgcn_s_waitcnt(WAITCNT(2, 7, 15));

    // pf(kt) from sP[kt&1] (published at previous barrier); b64, conflict-free
    const char* sPc = sPb + (kt & 1) * 2048;
    long pf[2][2];
    #pragma unroll
    for (int ks = 0; ks < 2; ++ks)
      #pragma unroll
      for (int mf = 0; mf < 2; ++mf) {
        int q = mf * 16 + l16;
        int c = ks * 8 + quad * 2;
        pf[ks][mf] = *(const long*)(sPc + q * 64 + ((c ^ (q & 14)) * 4));
      }

    // O += P @ [V, V^2]
    __builtin_amdgcn_s_setprio(1);
    #pragma unroll
    for (int ks = 0; ks < 2; ++ks)
      #pragma unroll
      for (int nf = 0; nf < 4; ++nf)
        #pragma unroll
        for (int mf = 0; mf < 2; ++mf)
          om[mf][nf] = MFMA_FP8(pf[ks][mf], vf[ks][nf], om[mf][nf]);
    __builtin_amdgcn_s_setprio(0);

    if (kt < 63) s_phase(kt + 1);   // reads sK buf (kt+1)&1, issues vf(kt+1)

    __builtin_amdgcn_s_waitcnt(WAITCNT(63, 7, 0));   // sP(kt+1) visible; all own LDS reads retired
    __builtin_amdgcn_s_barrier();                    // the ONE barrier per kt
  }

  // ---- finalize L: Lr holds per-(q=qh+l16) sums over this wave's 16-key stripe x all kt,
  //      split across quads; reduce quads then combine 4 key-stripe waves via atomics ----
  Lr += __shfl_xor(Lr, 16, 64);
  Lr += __shfl_xor(Lr, 32, 64);
  if (quad == 0) atomicAdd(&sL[qh + l16], Lr);
  // drain dead K prefetch DMA + publish sL before overlaying sE2 on sK
  __builtin_amdgcn_s_waitcnt(WAITCNT(0, 7, 0));
  __builtin_amdgcn_s_barrier();

  // ---- epilogue: waves 4..7 dump E2 numerators to LDS (f32 [256][32], 8-chunk swizzle) ----
  if (wid >= 4) {
    #pragma unroll
    for (int mf = 0; mf < 2; ++mf) {
      #pragma unroll
      for (int nf = 0; nf < 4; ++nf) {
        int ch = (wid - 4) * 64 + nf * 16 + l16;
        int cidx = (mf * 4 + quad) ^ (ch & 7);
        *(f32x4*)(sE2 + ch * 32 + cidx * 4) = om[mf][nf];
      }
    }
  }
  __syncthreads();

  if (wid < 4) {
    const float* meanc = stats + (0 * BB + b) * CC;     // content mean
    const float* rstdc = stats + (1 * BB + b) * CC;     // content rstd
    float linv[2][4];
    #pragma unroll
    for (int mf = 0; mf < 2; ++mf)
      #pragma unroll
      for (int r = 0; r < 4; ++r)
        linv[mf][r] = 1.0f / sL[mf * 16 + quad * 4 + r];
    #pragma unroll
    for (int nf = 0; nf < 4; ++nf) {
      int ch = cw + nf * 16 + l16;     // 0..255
      float mc = meanc[ch], rc = rstdc[ch];
      #pragma unroll
      for (int mf = 0; mf < 2; ++mf) {
        int cidx = (mf * 4 + quad) ^ (ch & 7);
        f32x4 vv = *(const f32x4*)(sE2 + ch * 32 + cidx * 4);
        f32x4 ov = om[mf][nf];
        #pragma unroll
        for (int r = 0; r < 4; ++r) {
          int row = mf * 16 + quad * 4 + r;
          float li = linv[mf][r];
          float ovr = (r == 0) ? ov.x : (r == 1) ? ov.y : (r == 2) ? ov.z : ov.w;
          float vvr = (r == 0) ? vv.x : (r == 1) ? vv.y : (r == 2) ? vv.z : vv.w;
          float M = ovr * li;
          float E2 = vvr * li;
          float S2 = E2 - M * M;
          float S = (S2 > 0.f) ? sqrtf(S2) : 0.f;
          size_t gi = (((size_t)b * NN + q0 + row) << 8) + ch;
          float xh = (content[gi] - mc) * rc;
          out[gi] = S * xh + M;
        }
      }
    }
  }
}

// ---------------- launcher ----------------
extern "C" void kernel_launch(void* const* d_in, const int* in_sizes, int n_in,
                              void* d_out, int out_size, void* d_ws, size_t ws_size,
                              hipStream_t stream) {
  const float* content = (const float*)d_in[0];
  const float* style   = (const float*)d_in[1];
  const float* Wq = (const float*)d_in[2];
  const float* bq = (const float*)d_in[3];
  const float* Wk = (const float*)d_in[4];
  const float* bk = (const float*)d_in[5];
  const float* Wv = (const float*)d_in[6];
  const float* bv = (const float*)d_in[7];
  char* ws = (char*)d_ws;

  float* sums        = (float*)(ws + 0);                 // 16 KB
  float* stats       = (float*)(ws + 16384);             // 16 KB
  unsigned char* Wt8 = (unsigned char*)(ws + 32768);     // 192 KB fp8 [3][256][256]
  unsigned char* Qn  = (unsigned char*)(ws + 229376);    // 4 MB fp8
  unsigned char* Kn  = (unsigned char*)(ws + 4423680);   // 4 MB fp8
  unsigned char* Vct = (unsigned char*)(ws + 8617984);   // 8 MB fp8 tiled [b][kt][ks][quad][512][8]
  float* outp = (float*)d_out;

  hipMemsetAsync(d_ws, 0, 16384, stream);
  hipLaunchKernelGGL(prep_kernel, dim3(1072), dim3(256), 0, stream,
                     content, style, Wq, Wk, Wv, sums, Wt8);
  hipLaunchKernelGGL(stats_finalize, dim3(8), dim3(256), 0, stream, sums, stats);
  hipLaunchKernelGGL(qkv_kernel, dim3(128, 3), dim3(256), 0, stream,
                     content, style, Wt8, bq, bk, bv, stats, Qn, Kn, Vct);
  hipLaunchKernelGGL(flash_kernel, dim3(512), dim3(512), 0, stream,
                     Qn, Kn, Vct, content, stats, outp);
}

// Round 21
// 204.000 us; speedup vs baseline: 2.1067x; 1.0771x over previous
//
#include <hip/hip_runtime.h>
#include <cstdint>

#define BB 4
#define NN 4096
#define CC 256

typedef __attribute__((ext_vector_type(8))) short bf16x8;
typedef __attribute__((ext_vector_type(4))) short bf16x4;
typedef __attribute__((ext_vector_type(4))) float f32x4;
typedef unsigned int u32;
typedef __attribute__((ext_vector_type(4))) u32 u32x4;
typedef __attribute__((ext_vector_type(2))) u32 u32x2;

#define MFMA_FP8(a, b, c)  __builtin_amdgcn_mfma_f32_16x16x32_fp8_fp8((a), (b), (c), 0, 0, 0)

// gfx9 s_waitcnt immediate: vmcnt[3:0]+[15:14], expcnt[6:4], lgkmcnt[11:8]
#define WAITCNT(vm, xp, lgkm) (((vm) & 0xF) | (((vm) >> 4) << 14) | ((xp) << 4) | ((lgkm) << 8))

__device__ __forceinline__ unsigned short f2bf(float f) {
  union { float f; unsigned u; } v; v.f = f;
  unsigned r = v.u + 0x7fffu + ((v.u >> 16) & 1u);
  return (unsigned short)(r >> 16);
}
// pack 4 f32 -> 4 fp8 e4m3 (OCP) in one dword, byte order a,b,c,d
__device__ __forceinline__ u32 pk4_fp8(float a, float b, float c, float d) {
  u32 v = (u32)__builtin_amdgcn_cvt_pk_fp8_f32(a, b, 0, false);
  v = (u32)__builtin_amdgcn_cvt_pk_fp8_f32(c, d, (int)v, true);
  return v;
}
__device__ __forceinline__ unsigned char fp8_1(float a) {
  return (unsigned char)(((u32)__builtin_amdgcn_cvt_pk_fp8_f32(a, a, 0, false)) & 0xff);
}

typedef __attribute__((address_space(3))) unsigned int lds_u32;
typedef __attribute__((address_space(1))) unsigned int glb_u32;

// async global->LDS, 16B per lane; LDS dest = wave-uniform base + lane*16
__device__ __forceinline__ void async_cp16(const void* g, void* l) {
  __builtin_amdgcn_global_load_lds((const glb_u32*)g,
                                   (lds_u32*)(unsigned)(unsigned long long)l,
                                   16, 0, 0);
}

// ---------------- prep: fused {stats_partial | W-transpose} (independent work, one launch) ----------------
// blocks [0,1024): instance-norm partial sums; blocks [1024,1072): Wt8[z][d][c] = fp8(W_z[c][d])
__global__ __launch_bounds__(256) void prep_kernel(const float* __restrict__ content,
                                                   const float* __restrict__ style,
                                                   const float* __restrict__ Wq,
                                                   const float* __restrict__ Wk,
                                                   const float* __restrict__ Wv,
                                                   float* __restrict__ sums,
                                                   unsigned char* __restrict__ Wt8) {
  __shared__ float sT[64 * 65];
  int gblk = blockIdx.x;
  if (gblk < 1024) {
    int t = gblk >> 9, b = (gblk >> 7) & 3, chunk = gblk & 127;
    const float* X = t ? style : content;
    int c = threadIdx.x;
    const float* base = X + ((size_t)b * NN + (size_t)chunk * 32) * CC + c;
    float s = 0.f, ss = 0.f;
    #pragma unroll 8
    for (int r = 0; r < 32; ++r) {
      float x = base[(size_t)r * CC];
      s += x; ss += x * x;
    }
    atomicAdd(&sums[((t * 2 + 0) * BB + b) * CC + c], s);
    atomicAdd(&sums[((t * 2 + 1) * BB + b) * CC + c], ss);
  } else {
    int blk = gblk - 1024;           // 48 = 3 * 16
    int z = blk / 16, tl = blk % 16;
    int c0 = (tl >> 2) * 64, d0 = (tl & 3) * 64;
    const float* W = (z == 0) ? Wq : ((z == 1) ? Wk : Wv);
    #pragma unroll
    for (int i = 0; i < 16; ++i) {
      int e = i * 256 + threadIdx.x;
      int c = e >> 6, d = e & 63;
      sT[c * 65 + d] = W[(size_t)(c0 + c) * CC + d0 + d];
    }
    __syncthreads();
    #pragma unroll
    for (int i = 0; i < 16; ++i) {
      int e = i * 256 + threadIdx.x;
      int d = e >> 6, c = e & 63;
      Wt8[(size_t)z * 65536 + (size_t)(d0 + d) * CC + c0 + c] = fp8_1(sT[c * 65 + d]);
    }
  }
}

__global__ __launch_bounds__(256) void stats_finalize(const float* __restrict__ sums,
                                                      float* __restrict__ stats) {
  int i = blockIdx.x * 256 + threadIdx.x;   // 2048 = 2*B*C
  int t = i >> 10, bc = i & 1023;
  float s = sums[(t * 2 + 0) * 1024 + bc];
  float ss = sums[(t * 2 + 1) * 1024 + bc];
  float m = s * (1.0f / NN);
  float var = ss * (1.0f / NN) - m * m;
  stats[(t * 2 + 0) * 1024 + bc] = m;
  stats[(t * 2 + 1) * 1024 + bc] = rsqrtf(var + 1e-5f);
}

// ---------------- QKV: fp8 GEMM, 128-row x 256-col tiles, 256 thr, 2 blocks/CU ----------------
// Vct output layout (flash-read-optimal tiles):
//   Vct[b][ktile:64][ks:2][quad:4][ch:512][key8:8] fp8, 2 MB per batch.
//   key within 64-key tile = ks*32 + quad*8 + key8; ch<256: V, ch>=256: V^2.
__global__ __launch_bounds__(256, 2) void qkv_kernel(
    const float* __restrict__ content, const float* __restrict__ style,
    const unsigned char* __restrict__ Wt8,
    const float* __restrict__ bq, const float* __restrict__ bk, const float* __restrict__ bv,
    const float* __restrict__ stats,
    unsigned char* __restrict__ Qn, unsigned char* __restrict__ Kn,
    unsigned char* __restrict__ Vct) {
  __shared__ __align__(16) char sW[32768];   // [256 d][128 c] fp8, slot8 = c16 ^ (d&7)
  __shared__ __align__(16) char sX[32768];   // [128 r][256 c] fp8, slot16 = c16 ^ (r&15); V-epilogue alias sOT[256][128]

  int tid = threadIdx.x;
  int wid = tid >> 6, lane = tid & 63, quad = lane >> 4, l16 = lane & 15;
  int uwid = __builtin_amdgcn_readfirstlane(wid);
  int tileid = blockIdx.x;      // 0..127 over B*N/128
  int z = blockIdx.y;           // 0=Q 1=K 2=V
  int gr0 = tileid * 128;       // global row over B*N
  int b = gr0 >> 12;

  const float* X = (z == 0) ? content : style;
  int statt = (z == 0) ? 0 : 1;
  const float* mean = stats + ((statt * 2 + 0) * BB + b) * CC;
  const float* rstd = stats + ((statt * 2 + 1) * BB + b) * CC;
  bool donorm = (z < 2);

  // ---- stage sX: x-hat (or raw style for V) quantized to fp8, swizzled ----
  #pragma unroll
  for (int i = 0; i < 8; ++i) {
    int lin = i * 256 + tid;
    int row = lin >> 4, c16 = lin & 15;
    int c = c16 * 16;
    const float* xr = X + (size_t)(gr0 + row) * CC + c;
    f32x4 x0 = *(const f32x4*)(xr + 0);
    f32x4 x1 = *(const f32x4*)(xr + 4);
    f32x4 x2 = *(const f32x4*)(xr + 8);
    f32x4 x3 = *(const f32x4*)(xr + 12);
    if (donorm) {
      f32x4 m0 = *(const f32x4*)(mean + c + 0), r0 = *(const f32x4*)(rstd + c + 0);
      f32x4 m1 = *(const f32x4*)(mean + c + 4), r1 = *(const f32x4*)(rstd + c + 4);
      f32x4 m2 = *(const f32x4*)(mean + c + 8), r2 = *(const f32x4*)(rstd + c + 8);
      f32x4 m3 = *(const f32x4*)(mean + c + 12), r3 = *(const f32x4*)(rstd + c + 12);
      x0 = (x0 - m0) * r0; x1 = (x1 - m1) * r1;
      x2 = (x2 - m2) * r2; x3 = (x3 - m3) * r3;
    }
    u32x4 pk;
    pk.x = pk4_fp8(x0.x, x0.y, x0.z, x0.w);
    pk.y = pk4_fp8(x1.x, x1.y, x1.z, x1.w);
    pk.z = pk4_fp8(x2.x, x2.y, x2.z, x2.w);
    pk.w = pk4_fp8(x3.x, x3.y, x3.z, x3.w);
    *(u32x4*)(sX + row * 256 + ((c16 ^ (row & 15)) * 16)) = pk;
  }

  f32x4 zero4 = {0.f, 0.f, 0.f, 0.f};
  f32x4 acc[2][16];
  #pragma unroll
  for (int i = 0; i < 2; ++i)
    #pragma unroll
    for (int j = 0; j < 16; ++j) acc[i][j] = zero4;

  const unsigned char* wb = Wt8 + (size_t)z * 65536;

  for (int half = 0; half < 2; ++half) {
    __syncthreads();   // sX visible (half0) / sW reads of prior half done (half1)
    // stage sW half: [256 d][128 c] fp8 from Wt8[z][d][half*128+..]
    #pragma unroll
    for (int it = 0; it < 8; ++it) {
      int L = it * 256 + wid * 64 + lane;
      int d = L >> 3;
      int c16 = (L & 7) ^ (d & 7);
      async_cp16(wb + (size_t)d * 256 + half * 128 + c16 * 16,
                 sW + (size_t)(it * 256 + uwid * 64) * 16);
    }
    __syncthreads();   // drain (compiler emits vmcnt(0) before barrier)

    // A-frags: rows wid*32 + mf*16 + l16, k-chunks kc*32 + quad*8 within this half
    long a[2][4];
    #pragma unroll
    for (int mf = 0; mf < 2; ++mf) {
      int row = wid * 32 + mf * 16 + l16;
      #pragma unroll
      for (int kc = 0; kc < 4; ++kc) {
        int chunk = half * 8 + kc * 2 + (quad >> 1);
        a[mf][kc] = *(const long*)(sX + row * 256 + ((chunk ^ (row & 15)) * 16) + (quad & 1) * 8);
      }
    }
    #pragma unroll
    for (int nf = 0; nf < 16; ++nf) {
      int d = nf * 16 + l16;
      #pragma unroll
      for (int kc = 0; kc < 4; ++kc) {
        long bw = *(const long*)(sW + d * 128 + (((kc * 2 + (quad >> 1)) ^ (d & 7)) * 16) + (quad & 1) * 8);
        acc[0][nf] = MFMA_FP8(a[0][kc], bw, acc[0][nf]);
        acc[1][nf] = MFMA_FP8(a[1][kc], bw, acc[1][nf]);
      }
    }
  }

  // ---- bias (before l2norm / store) ----
  const float* bias = (z == 0) ? bq : ((z == 1) ? bk : bv);
  #pragma unroll
  for (int nf = 0; nf < 16; ++nf) {
    float bb_ = bias[nf * 16 + l16];
    #pragma unroll
    for (int mf = 0; mf < 2; ++mf) {
      acc[mf][nf].x += bb_; acc[mf][nf].y += bb_;
      acc[mf][nf].z += bb_; acc[mf][nf].w += bb_;
    }
  }

  if (z < 2) {
    // l2-normalize rows (sum over all 256 cols lives in this wave), store fp8 row-major
    unsigned char* O = (z == 0) ? Qn : Kn;
    #pragma unroll
    for (int mf = 0; mf < 2; ++mf) {
      f32x4 ss = zero4;
      #pragma unroll
      for (int nf = 0; nf < 16; ++nf) ss += acc[mf][nf] * acc[mf][nf];
      #pragma unroll
      for (int m = 1; m < 16; m <<= 1) {
        ss.x += __shfl_xor(ss.x, m, 64);
        ss.y += __shfl_xor(ss.y, m, 64);
        ss.z += __shfl_xor(ss.z, m, 64);
        ss.w += __shfl_xor(ss.w, m, 64);
      }
      f32x4 rq;
      rq.x = rsqrtf(ss.x + 1e-12f); rq.y = rsqrtf(ss.y + 1e-12f);
      rq.z = rsqrtf(ss.z + 1e-12f); rq.w = rsqrtf(ss.w + 1e-12f);
      int r0 = wid * 32 + mf * 16 + quad * 4;
      #pragma unroll
      for (int nf = 0; nf < 16; ++nf) {
        int col = nf * 16 + l16;
        u32 p01 = (u32)__builtin_amdgcn_cvt_pk_fp8_f32(acc[mf][nf].x * rq.x, acc[mf][nf].y * rq.y, 0, false);
        u32 p23 = (u32)__builtin_amdgcn_cvt_pk_fp8_f32(acc[mf][nf].z * rq.z, acc[mf][nf].w * rq.w, 0, false);
        O[(size_t)(gr0 + r0 + 0) * CC + col] = (unsigned char)(p01 & 0xff);
        O[(size_t)(gr0 + r0 + 1) * CC + col] = (unsigned char)((p01 >> 8) & 0xff);
        O[(size_t)(gr0 + r0 + 2) * CC + col] = (unsigned char)(p23 & 0xff);
        O[(size_t)(gr0 + r0 + 3) * CC + col] = (unsigned char)((p23 >> 8) & 0xff);
      }
    }
  } else {
    // V: two passes through sOT (alias sX): pass0 = V, pass1 = V^2.
    // Store to tiled Vct[b][ktile][ks][quad][ch][8]; 8B stores, ch-contiguous across threads.
    char* sOT = sX;   // [256 ch][128 row] fp8, chunk j' = j ^ (ch&7)
    int n_in_b = gr0 & (NN - 1);        // multiple of 128
    int ktbase = n_in_b >> 6;           // first of 2 ktiles covered by this 128-row window
    __syncthreads();   // all sX A-reads done
    #pragma unroll
    for (int pass = 0; pass < 2; ++pass) {
      #pragma unroll
      for (int mf = 0; mf < 2; ++mf) {
        int j = wid * 2 + mf;
        #pragma unroll
        for (int nf = 0; nf < 16; ++nf) {
          int col = nf * 16 + l16;
          f32x4 v = acc[mf][nf];
          f32x4 w = pass ? (v * v) : v;
          u32 pk = pk4_fp8(w.x, w.y, w.z, w.w);
          *(u32*)(sOT + col * 128 + ((j ^ (col & 7)) * 16) + quad * 4) = pk;
        }
      }
      __syncthreads();
      int ch = pass * 256 + tid;   // 0..511
      unsigned char* vb = Vct + (size_t)b * 2097152 + (size_t)ch * 8;
      #pragma unroll
      for (int j = 0; j < 8; ++j) {
        u32x4 val = *(const u32x4*)(sOT + tid * 128 + ((j ^ (tid & 7)) * 16));
        int ktile = ktbase + (j >> 2);
        int ks = (j >> 1) & 1;
        int q0 = (j & 1) * 2;                       // 16B chunk = quads q0, q0+1
        unsigned char* basep = vb + (size_t)((ktile * 2 + ks) * 4 + q0) * 4096;
        u32x2 lo; lo.x = val.x; lo.y = val.y;
        u32x2 hi; hi.x = val.z; hi.y = val.w;
        *(u32x2*)(basep) = lo;
        *(u32x2*)(basep + 4096) = hi;
      }
      __syncthreads();
    }
  }
}

// ---------------- flash attention (verified R7 structure, setprio reverted): q-tile 32, V direct ----------------
__global__ __launch_bounds__(512, 4) void flash_kernel(
    const unsigned char* __restrict__ Qn,
    const unsigned char* __restrict__ Kn,
    const unsigned char* __restrict__ Vct,     // [b][kt][ks][quad][512ch][8] fp8 tiles
    const float* __restrict__ content,
    const float* __restrict__ stats,
    float* __restrict__ out) {
  // layout: sK 2x16K | sP 2x2K | sL 128B; epilogue overlays f32 sE2[256][32] on sK
  __shared__ __align__(16) char smem[32768 + 4096 + 128];
  char* sKb = smem;
  char* sPb = smem + 32768;
  float* sL = (float*)(smem + 36864);
  float* sE2 = (float*)smem;

  int tid = threadIdx.x;
  int wid = tid >> 6, lane = tid & 63, quad = lane >> 4, l16 = lane & 15;
  int uwid = __builtin_amdgcn_readfirstlane(wid);

  int id = blockIdx.x;                       // 512 blocks; XCD swizzle: batch b on XCDs {2b,2b+1}
  int b = (id >> 1) & 3;
  int tile = ((id >> 3) << 1) | (id & 1);    // 0..127
  int q0 = tile * 32;

  int qh = (wid >> 2) * 16;        // S-phase q half (16 q per wave)
  int kb0 = (wid & 3) * 16;        // S-phase key stripe (16 keys)
  int cw = wid * 64;               // PV ch base (64 of 512)

  // Q B-frags fp8 in registers: lane holds Q[q = qh+l16][k = kf*32+quad*8..+7]
  long qf[8];
  {
    int row = q0 + qh + l16;
    const unsigned char* base = Qn + (((size_t)b * NN + row) << 8);
    #pragma unroll
    for (int kf = 0; kf < 8; ++kf)
      qf[kf] = *(const long*)(base + kf * 32 + quad * 8);
  }
  __builtin_amdgcn_s_waitcnt(WAITCNT(0, 7, 15));   // drain qf: loop vmcnt counts staging+vf only

  if (tid < 32) sL[tid] = 0.f;

  const unsigned char* kbp = Kn + (((size_t)b * NN) << 8);
  // V: per-lane base offset within a 32KB kt-tile: + ks*16384 + nf*128 later
  const unsigned char* vbp = Vct + (size_t)b * 2097152 + quad * 4096 + (size_t)(cw + l16) * 8;

  // K tile [64 key][256 c] fp8 = 16 KB; 16B chunks swizzled: slot = c16 ^ (key&15)
  auto stageK = [&](int k0, int buf) {
    char* dst = sKb + buf * 16384;
    #pragma unroll
    for (int it = 0; it < 2; ++it) {
      int L = it * 512 + wid * 64 + lane;
      int ky = L >> 4, s = L & 15;
      int c16 = s ^ (ky & 15);
      async_cp16(kbp + (((size_t)(k0 + ky)) << 8) + c16 * 16,
                 dst + (size_t)(it * 512 + uwid * 64) * 16);
    }
  };

  f32x4 zero4 = {0.f, 0.f, 0.f, 0.f};
  f32x4 om[2][4];
  #pragma unroll
  for (int i = 0; i < 2; ++i)
    #pragma unroll
    for (int j = 0; j < 4; ++j) om[i][j] = zero4;
  float Lr = 0.f;
  long vf[2][4];    // V fragments for tile kt, global-loaded during s_phase(kt)

  int krow = kb0 + l16;
  int krowoff = krow * 256;
  int khalf = (quad & 1) * 8;

  // S^T(kt) + exp + sP(kt) write + issue vf(kt) global loads (consumed by PV(kt) next iter)
  auto s_phase = [&](int kt) {
    const char* sKc = sKb + (kt & 1) * 16384;
    char* sPc = sPb + (kt & 1) * 2048;
    f32x4 ta = zero4, tb = zero4;     // ILP-2 split of the 8-deep K-chain
    #pragma unroll
    for (int kf = 0; kf < 8; kf += 2) {
      int sa = (kf * 2 + (quad >> 1)) ^ (krow & 15);
      long aka = *(const long*)(sKc + krowoff + sa * 16 + khalf);
      ta = MFMA_FP8(aka, qf[kf], ta);     // D[key][q], keys quad*4+reg, q=l16
      int sb = ((kf + 1) * 2 + (quad >> 1)) ^ (krow & 15);
      long akb = *(const long*)(sKc + krowoff + sb * 16 + khalf);
      tb = MFMA_FP8(akb, qf[kf + 1], tb);
    }
    f32x4 sv = ta + tb;
    float p0 = __expf(sv.x), p1 = __expf(sv.y), p2 = __expf(sv.z), p3 = __expf(sv.w);
    Lr += p0 + p1 + p2 + p3;          // sum over this lane's 4 keys for q
    u32 w = pk4_fp8(p0, p1, p2, p3);  // bytes = keys (kb0+quad*4)+0..3
    int q = qh + l16;
    int c = (kb0 >> 2) + quad;        // 4B-chunk = key/4
    *(u32*)(sPc + q * 64 + ((c ^ (q & 14)) * 4)) = w;
    // issue vf(kt): 8 x global b64, 128B-contiguous per 16-lane group (L2-resident)
    const unsigned char* vt = vbp + (size_t)kt * 32768;
    #pragma unroll
    for (int ks = 0; ks < 2; ++ks)
      #pragma unroll
      for (int nf = 0; nf < 4; ++nf)
        vf[ks][nf] = *(const long*)(vt + ks * 16384 + nf * 128);
  };

  // prologue: K 2-deep; S(0) + sP(0) + vf(0) issue; publish
  stageK(0, 0);  stageK(64, 1);
  __builtin_amdgcn_s_waitcnt(WAITCNT(2, 7, 15));   // K(0) landed; K(1) in flight
  __builtin_amdgcn_s_barrier();
  s_phase(0);
  __builtin_amdgcn_s_waitcnt(WAITCNT(63, 7, 0));   // sP(0) + own LDS reads done
  __builtin_amdgcn_s_barrier();

  for (int kt = 0; kt < 64; ++kt) {
    // stage K(kt+2) into buf (kt&1)
    stageK(((kt + 2) & 63) * 64, kt & 1);    // wrap: dead prefetch on last iters, drained in epilogue

    // vf(kt) + K(kt+1) landed (2 newest outstanding = K(kt+2)'s staging)
    __builtin_amdgcn_s_waitcnt(WAITCNT(2, 7, 15));

    // pf(kt) from sP[kt&1] (published at previous barrier); b64, conflict-free
    const char* sPc = sPb + (kt & 1) * 2048;
    long pf[2][2];
    #pragma unroll
    for (int ks = 0; ks < 2; ++ks)
      #pragma unroll
      for (int mf = 0; mf < 2; ++mf) {
        int q = mf * 16 + l16;
        int c = ks * 8 + quad * 2;
        pf[ks][mf] = *(const long*)(sPc + q * 64 + ((c ^ (q & 14)) * 4));
      }

    // O += P @ [V, V^2]
    #pragma unroll
    for (int ks = 0; ks < 2; ++ks)
      #pragma unroll
      for (int nf = 0; nf < 4; ++nf)
        #pragma unroll
        for (int mf = 0; mf < 2; ++mf)
          om[mf][nf] = MFMA_FP8(pf[ks][mf], vf[ks][nf], om[mf][nf]);

    if (kt < 63) s_phase(kt + 1);   // reads sK buf (kt+1)&1, issues vf(kt+1)

    __builtin_amdgcn_s_waitcnt(WAITCNT(63, 7, 0));   // sP(kt+1) visible; all own LDS reads retired
    __builtin_amdgcn_s_barrier();                    // the ONE barrier per kt
  }

  // ---- finalize L: Lr holds per-(q=qh+l16) sums over this wave's 16-key stripe x all kt,
  //      split across quads; reduce quads then combine 4 key-stripe waves via atomics ----
  Lr += __shfl_xor(Lr, 16, 64);
  Lr += __shfl_xor(Lr, 32, 64);
  if (quad == 0) atomicAdd(&sL[qh + l16], Lr);
  // drain dead K prefetch DMA + publish sL before overlaying sE2 on sK
  __builtin_amdgcn_s_waitcnt(WAITCNT(0, 7, 0));
  __builtin_amdgcn_s_barrier();

  // ---- epilogue: waves 4..7 dump E2 numerators to LDS (f32 [256][32], 8-chunk swizzle) ----
  if (wid >= 4) {
    #pragma unroll
    for (int mf = 0; mf < 2; ++mf) {
      #pragma unroll
      for (int nf = 0; nf < 4; ++nf) {
        int ch = (wid - 4) * 64 + nf * 16 + l16;
        int cidx = (mf * 4 + quad) ^ (ch & 7);
        *(f32x4*)(sE2 + ch * 32 + cidx * 4) = om[mf][nf];
      }
    }
  }
  __syncthreads();

  if (wid < 4) {
    const float* meanc = stats + (0 * BB + b) * CC;     // content mean
    const float* rstdc = stats + (1 * BB + b) * CC;     // content rstd
    float linv[2][4];
    #pragma unroll
    for (int mf = 0; mf < 2; ++mf)
      #pragma unroll
      for (int r = 0; r < 4; ++r)
        linv[mf][r] = 1.0f / sL[mf * 16 + quad * 4 + r];
    #pragma unroll
    for (int nf = 0; nf < 4; ++nf) {
      int ch = cw + nf * 16 + l16;     // 0..255
      float mc = meanc[ch], rc = rstdc[ch];
      #pragma unroll
      for (int mf = 0; mf < 2; ++mf) {
        int cidx = (mf * 4 + quad) ^ (ch & 7);
        f32x4 vv = *(const f32x4*)(sE2 + ch * 32 + cidx * 4);
        f32x4 ov = om[mf][nf];
        #pragma unroll
        for (int r = 0; r < 4; ++r) {
          int row = mf * 16 + quad * 4 + r;
          float li = linv[mf][r];
          float ovr = (r == 0) ? ov.x : (r == 1) ? ov.y : (r == 2) ? ov.z : ov.w;
          float vvr = (r == 0) ? vv.x : (r == 1) ? vv.y : (r == 2) ? vv.z : vv.w;
          float M = ovr * li;
          float E2 = vvr * li;
          float S2 = E2 - M * M;
          float S = (S2 > 0.f) ? sqrtf(S2) : 0.f;
          size_t gi = (((size_t)b * NN + q0 + row) << 8) + ch;
          float xh = (content[gi] - mc) * rc;
          out[gi] = S * xh + M;
        }
      }
    }
  }
}

// ---------------- launcher ----------------
extern "C" void kernel_launch(void* const* d_in, const int* in_sizes, int n_in,
                              void* d_out, int out_size, void* d_ws, size_t ws_size,
                              hipStream_t stream) {
  const float* content = (const float*)d_in[0];
  const float* style   = (const float*)d_in[1];
  const float* Wq = (const float*)d_in[2];
  const float* bq = (const float*)d_in[3];
  const float* Wk = (const float*)d_in[4];
  const float* bk = (const float*)d_in[5];
  const float* Wv = (const float*)d_in[6];
  const float* bv = (const float*)d_in[7];
  char* ws = (char*)d_ws;

  float* sums        = (float*)(ws + 0);                 // 16 KB
  float* stats       = (float*)(ws + 16384);             // 16 KB
  unsigned char* Wt8 = (unsigned char*)(ws + 32768);     // 192 KB fp8 [3][256][256]
  unsigned char* Qn  = (unsigned char*)(ws + 229376);    // 4 MB fp8
  unsigned char* Kn  = (unsigned char*)(ws + 4423680);   // 4 MB fp8
  unsigned char* Vct = (unsigned char*)(ws + 8617984);   // 8 MB fp8 tiled [b][kt][ks][quad][512][8]
  float* outp = (float*)d_out;

  hipMemsetAsync(d_ws, 0, 16384, stream);
  hipLaunchKernelGGL(prep_kernel, dim3(1072), dim3(256), 0, stream,
                     content, style, Wq, Wk, Wv, sums, Wt8);
  hipLaunchKernelGGL(stats_finalize, dim3(8), dim3(256), 0, stream, sums, stats);
  hipLaunchKernelGGL(qkv_kernel, dim3(128, 3), dim3(256), 0, stream,
                     content, style, Wt8, bq, bk, bv, stats, Qn, Kn, Vct);
  hipLaunchKernelGGL(flash_kernel, dim3(512), dim3(512), 0, stream,
                     Qn, Kn, Vct, content, stats, outp);
}